// Round 1
// baseline (4330.627 us; speedup 1.0000x reference)
//
#include <hip/hip_runtime.h>

#define NN 100000
#define NE 1600000
#define DIN 128
#define HDIM 64
#define DOUT 40
#define EPS 1e-5f

// ---------------- degree / norm ----------------
__global__ __launch_bounds__(256) void fill_ones(float* p, int n) {
    for (int i = blockIdx.x * blockDim.x + threadIdx.x; i < n; i += gridDim.x * blockDim.x)
        p[i] = 1.0f;
}

__global__ __launch_bounds__(256) void deg_kernel(const int* __restrict__ dst, float* deg) {
    for (int e = blockIdx.x * blockDim.x + threadIdx.x; e < NE; e += gridDim.x * blockDim.x)
        atomicAdd(&deg[dst[e]], 1.0f);
}

__global__ __launch_bounds__(256) void rsqrt_kernel(float* d, int n) {
    for (int i = blockIdx.x * blockDim.x + threadIdx.x; i < n; i += gridDim.x * blockDim.x)
        d[i] = rsqrtf(d[i]);
}

// ---------------- dense GEMM: h[N,64] = x[N,K] @ W[K,64] ----------------
template <int K>
__global__ __launch_bounds__(256) void gemm_k(const float* __restrict__ x,
                                              const float* __restrict__ W,
                                              float* __restrict__ h) {
    __shared__ float xs[4][K];
    const int tid = threadIdx.x;
    const int row0 = blockIdx.x * 4;
    for (int i = tid; i < 4 * K; i += 256) {
        int r = i / K, k = i - r * K;
        xs[r][k] = x[(row0 + r) * K + k];
    }
    __syncthreads();
    const int r = tid >> 6, c = tid & 63;
    float acc = 0.f;
#pragma unroll 8
    for (int k = 0; k < K; ++k) acc += xs[r][k] * W[k * 64 + c];
    h[(row0 + r) * 64 + c] = acc;
}

// ---------------- y = h * selfnorm (init, no memset needed) ----------------
__global__ __launch_bounds__(256) void selfloop_kernel(const float* __restrict__ h,
                                                       const float* __restrict__ dis,
                                                       float* __restrict__ y) {
    for (int i = blockIdx.x * blockDim.x + threadIdx.x; i < NN * 16; i += gridDim.x * blockDim.x) {
        int row = i >> 4;
        float s = dis[row];
        s = s * s;
        float4 v = ((const float4*)h)[i];
        v.x *= s; v.y *= s; v.z *= s; v.w *= s;
        ((float4*)y)[i] = v;
    }
}

// ---------------- edge scatter: y[dst] += h[src]*norm ----------------
__global__ __launch_bounds__(256) void agg_kernel(const int* __restrict__ ei,
                                                  const float* __restrict__ dis,
                                                  const float* __restrict__ h,
                                                  float* __restrict__ y) {
    for (long long idx = blockIdx.x * blockDim.x + threadIdx.x; idx < (long long)NE * 16;
         idx += (long long)gridDim.x * blockDim.x) {
        int e = (int)(idx >> 4), q = (int)(idx & 15);
        int s = ei[e];
        int d = ei[NE + e];
        float nrm = dis[s] * dis[d];
        float4 v = ((const float4*)(h + (long long)s * 64))[q];
        float* yp = y + (long long)d * 64 + q * 4;
        atomicAdd(yp + 0, v.x * nrm);
        atomicAdd(yp + 1, v.y * nrm);
        atomicAdd(yp + 2, v.z * nrm);
        atomicAdd(yp + 3, v.w * nrm);
    }
}

// ---------------- per-channel sum / sumsq ----------------
__global__ __launch_bounds__(256) void stats_kernel(const float* __restrict__ y, float* stats) {
    const int tid = threadIdx.x;
    const int c = tid & 63, rg = tid >> 6;
    float s = 0.f, s2 = 0.f;
    for (int row = blockIdx.x * 4 + rg; row < NN; row += gridDim.x * 4) {
        float v = y[(long long)row * 64 + c];
        s += v;
        s2 += v * v;
    }
    __shared__ float ls[256], ls2[256];
    ls[tid] = s; ls2[tid] = s2;
    __syncthreads();
    if (tid < 64) {
        s = ls[tid] + ls[tid + 64] + ls[tid + 128] + ls[tid + 192];
        s2 = ls2[tid] + ls2[tid + 64] + ls2[tid + 128] + ls2[tid + 192];
        atomicAdd(&stats[tid], s);
        atomicAdd(&stats[64 + tid], s2);
    }
}

// ---------------- BN (batch stats) + ReLU, in place ----------------
__global__ __launch_bounds__(256) void bn_relu_kernel(float* __restrict__ x,
                                                      const float* __restrict__ stats,
                                                      const float* __restrict__ g,
                                                      const float* __restrict__ beta) {
    const float invN = 1.0f / NN;
    for (int i = blockIdx.x * blockDim.x + threadIdx.x; i < NN * 16; i += gridDim.x * blockDim.x) {
        int q = i & 15;
        int c0 = q * 4;
        float4 v = ((const float4*)x)[i];
        float o[4] = {v.x, v.y, v.z, v.w};
#pragma unroll
        for (int j = 0; j < 4; ++j) {
            float mc = stats[c0 + j] * invN;
            float var = stats[64 + c0 + j] * invN - mc * mc;
            float sc = g[c0 + j] * rsqrtf(var + EPS);
            float sh = beta[c0 + j] - mc * sc;
            o[j] = fmaxf(fmaf(o[j], sc, sh), 0.f);
        }
        v.x = o[0]; v.y = o[1]; v.z = o[2]; v.w = o[3];
        ((float4*)x)[i] = v;
    }
}

// ---------------- JK max + final linear ----------------
__global__ __launch_bounds__(256) void final_kernel(const float* __restrict__ x1,
                                                    const float* __restrict__ x2,
                                                    const float* __restrict__ x3,
                                                    const float* __restrict__ b3,
                                                    const float* __restrict__ Wf,
                                                    const float* __restrict__ bf,
                                                    float* __restrict__ out) {
    __shared__ float m[4][64];
    const int tid = threadIdx.x;
    const int r = tid >> 6, c = tid & 63;
    const int row = blockIdx.x * 4 + r;
    long long o = (long long)row * 64 + c;
    float v = fmaxf(fmaxf(x1[o], x2[o]), x3[o] + b3[c]);
    m[r][c] = v;
    __syncthreads();
    if (c < DOUT) {
        float acc = bf[c];
#pragma unroll
        for (int k = 0; k < 64; ++k) acc += m[r][k] * Wf[k * DOUT + c];
        out[(long long)row * DOUT + c] = acc;
    }
}

extern "C" void kernel_launch(void* const* d_in, const int* in_sizes, int n_in,
                              void* d_out, int out_size, void* d_ws, size_t ws_size,
                              hipStream_t stream) {
    const float* node_feat = (const float*)d_in[0];
    const int*   ei        = (const int*)d_in[1];
    const float* W1 = (const float*)d_in[2];
    const float* g1 = (const float*)d_in[4];
    const float* beta1 = (const float*)d_in[5];
    const float* W2 = (const float*)d_in[6];
    const float* g2 = (const float*)d_in[8];
    const float* beta2 = (const float*)d_in[9];
    const float* W3 = (const float*)d_in[10];
    const float* b3 = (const float*)d_in[11];
    const float* Wf = (const float*)d_in[12];
    const float* bf = (const float*)d_in[13];
    float* out = (float*)d_out;

    float* ws  = (float*)d_ws;
    float* dis = ws;                       // N
    float* h   = dis + NN;                 // N*64
    float* x1  = h + (long long)NN * 64;   // N*64
    float* x2  = x1 + (long long)NN * 64;  // N*64
    float* x3  = x2 + (long long)NN * 64;  // N*64
    float* stats = x3 + (long long)NN * 64; // 128

    const int B = 256;
    const int gElem = 2048;     // grid-stride cover
    const int gRows = NN / 4;   // 25000, one block per 4 rows

    // degree + normalization
    fill_ones<<<512, B, 0, stream>>>(dis, NN);
    deg_kernel<<<gElem, B, 0, stream>>>(ei + NE, dis);
    rsqrt_kernel<<<512, B, 0, stream>>>(dis, NN);

    // ---- layer 1 ----
    gemm_k<DIN><<<gRows, B, 0, stream>>>(node_feat, W1, h);
    selfloop_kernel<<<gElem, B, 0, stream>>>(h, dis, x1);
    agg_kernel<<<gElem, B, 0, stream>>>(ei, dis, h, x1);
    hipMemsetAsync(stats, 0, 128 * sizeof(float), stream);
    stats_kernel<<<512, B, 0, stream>>>(x1, stats);
    bn_relu_kernel<<<gElem, B, 0, stream>>>(x1, stats, g1, beta1);

    // ---- layer 2 ----
    gemm_k<HDIM><<<gRows, B, 0, stream>>>(x1, W2, h);
    selfloop_kernel<<<gElem, B, 0, stream>>>(h, dis, x2);
    agg_kernel<<<gElem, B, 0, stream>>>(ei, dis, h, x2);
    hipMemsetAsync(stats, 0, 128 * sizeof(float), stream);
    stats_kernel<<<512, B, 0, stream>>>(x2, stats);
    bn_relu_kernel<<<gElem, B, 0, stream>>>(x2, stats, g2, beta2);

    // ---- layer 3 (no BN/ReLU; b3 folded into final) ----
    gemm_k<HDIM><<<gRows, B, 0, stream>>>(x2, W3, h);
    selfloop_kernel<<<gElem, B, 0, stream>>>(h, dis, x3);
    agg_kernel<<<gElem, B, 0, stream>>>(ei, dis, h, x3);

    // ---- JK max + final linear ----
    final_kernel<<<gRows, B, 0, stream>>>(x1, x2, x3, b3, Wf, bf, out);
}

// Round 2
// 693.539 us; speedup vs baseline: 6.2442x; 6.2442x over previous
//
#include <hip/hip_runtime.h>

#define NN 100000
#define NE 1600000
#define DIN 128
#define HDIM 64
#define DOUT 40
#define EPS 1e-5f

#define SCAN_CHUNK 2048
#define SCAN_NBLK ((NN + SCAN_CHUNK - 1) / SCAN_CHUNK)  // 49

// ---------------- CSR build ----------------
__global__ __launch_bounds__(256) void count_kernel(const int* __restrict__ dst,
                                                    int* __restrict__ cnt) {
    for (int e = blockIdx.x * blockDim.x + threadIdx.x; e < NE; e += gridDim.x * blockDim.x)
        atomicAdd(&cnt[dst[e]], 1);
}

__global__ __launch_bounds__(256) void dis_kernel(const int* __restrict__ cnt,
                                                  float* __restrict__ dis) {
    for (int i = blockIdx.x * blockDim.x + threadIdx.x; i < NN; i += gridDim.x * blockDim.x)
        dis[i] = rsqrtf((float)(cnt[i] + 1));   // +1 self loop
}

// partial sums per 2048-chunk
__global__ __launch_bounds__(256) void scan_partial(const int* __restrict__ cnt,
                                                    int* __restrict__ bsum) {
    __shared__ int ls[256];
    const int tid = threadIdx.x;
    int base = blockIdx.x * SCAN_CHUNK + tid * 8;
    int s = 0;
#pragma unroll
    for (int k = 0; k < 8; ++k) {
        int idx = base + k;
        s += (idx < NN) ? cnt[idx] : 0;
    }
    ls[tid] = s;
    __syncthreads();
    for (int off = 128; off > 0; off >>= 1) {
        if (tid < off) ls[tid] += ls[tid + off];
        __syncthreads();
    }
    if (tid == 0) bsum[blockIdx.x] = ls[0];
}

// exclusive scan of block sums (tiny), also writes off[NN] = NE
__global__ __launch_bounds__(64) void scan_bsum(int* __restrict__ bsum, int* __restrict__ off) {
    if (threadIdx.x == 0) {
        int run = 0;
        for (int i = 0; i < SCAN_NBLK; ++i) {
            int t = bsum[i];
            bsum[i] = run;
            run += t;
        }
        off[NN] = NE;
    }
}

// scatter exclusive prefix: off[i] = bsum_ex[blk] + intra-block exclusive
__global__ __launch_bounds__(256) void scan_scatter(const int* __restrict__ cnt,
                                                    const int* __restrict__ bsum,
                                                    int* __restrict__ off) {
    __shared__ int part[256];
    const int tid = threadIdx.x;
    const int base = blockIdx.x * SCAN_CHUNK + tid * 8;
    int v[8];
    int s = 0;
#pragma unroll
    for (int k = 0; k < 8; ++k) {
        int idx = base + k;
        v[k] = (idx < NN) ? cnt[idx] : 0;
        s += v[k];
    }
    part[tid] = s;
    __syncthreads();
    if (tid == 0) {
        int run = 0;
        for (int i = 0; i < 256; ++i) {
            int t = part[i];
            part[i] = run;
            run += t;
        }
    }
    __syncthreads();
    int run = bsum[blockIdx.x] + part[tid];
#pragma unroll
    for (int k = 0; k < 8; ++k) {
        int idx = base + k;
        if (idx < NN) off[idx] = run;
        run += v[k];
    }
}

__global__ __launch_bounds__(256) void fill_kernel(const int* __restrict__ ei,
                                                   const float* __restrict__ dis,
                                                   int* __restrict__ cur,
                                                   int2* __restrict__ edata) {
    for (int e = blockIdx.x * blockDim.x + threadIdx.x; e < NE; e += gridDim.x * blockDim.x) {
        int s = ei[e];
        int d = ei[NE + e];
        int pos = atomicAdd(&cur[d], 1);
        edata[pos] = make_int2(s, __float_as_int(dis[s] * dis[d]));
    }
}

// ---------------- dense GEMM: h[N,64] = x[N,K] @ W[K,64] ----------------
template <int K>
__global__ __launch_bounds__(256) void gemm_k(const float* __restrict__ x,
                                              const float* __restrict__ W,
                                              float* __restrict__ h) {
    __shared__ float xs[4][K];
    const int tid = threadIdx.x;
    const int row0 = blockIdx.x * 4;
    for (int i = tid; i < 4 * K; i += 256) {
        int r = i / K, k = i - r * K;
        xs[r][k] = x[(row0 + r) * K + k];
    }
    __syncthreads();
    const int r = tid >> 6, c = tid & 63;
    float acc = 0.f;
#pragma unroll 8
    for (int k = 0; k < K; ++k) acc += xs[r][k] * W[k * 64 + c];
    h[(row0 + r) * 64 + c] = acc;
}

// ---------------- CSR gather: y[n] = h[n]*dis[n]^2 + sum_in h[src]*norm ----------------
__global__ __launch_bounds__(256) void agg_csr(const int* __restrict__ off,
                                               const int2* __restrict__ edata,
                                               const float* __restrict__ dis,
                                               const float* __restrict__ h,
                                               float* __restrict__ y) {
    const int node = blockIdx.x * 4 + (threadIdx.x >> 6);  // one wave per node
    const int c = threadIdx.x & 63;
    const float s = dis[node];
    float acc = h[node * 64 + c] * s * s;
    const int jb = off[node], je = off[node + 1];
#pragma unroll 4
    for (int j = jb; j < je; ++j) {
        int2 p = edata[j];
        acc = fmaf(h[p.x * 64 + c], __int_as_float(p.y), acc);
    }
    y[node * 64 + c] = acc;
}

// ---------------- per-channel sum / sumsq ----------------
__global__ __launch_bounds__(256) void stats_kernel(const float* __restrict__ y, float* stats) {
    const int tid = threadIdx.x;
    const int c = tid & 63, rg = tid >> 6;
    float s = 0.f, s2 = 0.f;
    for (int row = blockIdx.x * 4 + rg; row < NN; row += gridDim.x * 4) {
        float v = y[row * 64 + c];
        s += v;
        s2 += v * v;
    }
    __shared__ float ls[256], ls2[256];
    ls[tid] = s; ls2[tid] = s2;
    __syncthreads();
    if (tid < 64) {
        s = ls[tid] + ls[tid + 64] + ls[tid + 128] + ls[tid + 192];
        s2 = ls2[tid] + ls2[tid + 64] + ls2[tid + 128] + ls2[tid + 192];
        atomicAdd(&stats[tid], s);
        atomicAdd(&stats[64 + tid], s2);
    }
}

// ---------------- BN (batch stats) + ReLU, in place ----------------
__global__ __launch_bounds__(256) void bn_relu_kernel(float* __restrict__ x,
                                                      const float* __restrict__ stats,
                                                      const float* __restrict__ g,
                                                      const float* __restrict__ beta) {
    const float invN = 1.0f / NN;
    for (int i = blockIdx.x * blockDim.x + threadIdx.x; i < NN * 16; i += gridDim.x * blockDim.x) {
        int q = i & 15;
        int c0 = q * 4;
        float4 v = ((const float4*)x)[i];
        float o[4] = {v.x, v.y, v.z, v.w};
#pragma unroll
        for (int j = 0; j < 4; ++j) {
            float mc = stats[c0 + j] * invN;
            float var = stats[64 + c0 + j] * invN - mc * mc;
            float sc = g[c0 + j] * rsqrtf(var + EPS);
            float sh = beta[c0 + j] - mc * sc;
            o[j] = fmaxf(fmaf(o[j], sc, sh), 0.f);
        }
        v.x = o[0]; v.y = o[1]; v.z = o[2]; v.w = o[3];
        ((float4*)x)[i] = v;
    }
}

// ---------------- JK max + final linear ----------------
__global__ __launch_bounds__(256) void final_kernel(const float* __restrict__ x1,
                                                    const float* __restrict__ x2,
                                                    const float* __restrict__ x3,
                                                    const float* __restrict__ b3,
                                                    const float* __restrict__ Wf,
                                                    const float* __restrict__ bf,
                                                    float* __restrict__ out) {
    __shared__ float m[4][64];
    const int tid = threadIdx.x;
    const int r = tid >> 6, c = tid & 63;
    const int row = blockIdx.x * 4 + r;
    int o = row * 64 + c;
    float v = fmaxf(fmaxf(x1[o], x2[o]), x3[o] + b3[c]);
    m[r][c] = v;
    __syncthreads();
    if (c < DOUT) {
        float acc = bf[c];
#pragma unroll
        for (int k = 0; k < 64; ++k) acc += m[r][k] * Wf[k * DOUT + c];
        out[row * DOUT + c] = acc;
    }
}

extern "C" void kernel_launch(void* const* d_in, const int* in_sizes, int n_in,
                              void* d_out, int out_size, void* d_ws, size_t ws_size,
                              hipStream_t stream) {
    const float* node_feat = (const float*)d_in[0];
    const int*   ei        = (const int*)d_in[1];
    const float* W1 = (const float*)d_in[2];
    const float* g1 = (const float*)d_in[4];
    const float* beta1 = (const float*)d_in[5];
    const float* W2 = (const float*)d_in[6];
    const float* g2 = (const float*)d_in[8];
    const float* beta2 = (const float*)d_in[9];
    const float* W3 = (const float*)d_in[10];
    const float* b3 = (const float*)d_in[11];
    const float* Wf = (const float*)d_in[12];
    const float* bf = (const float*)d_in[13];
    float* out = (float*)d_out;

    // workspace layout
    float* ws  = (float*)d_ws;
    float* dis = ws;                         // N
    float* h   = dis + NN;                   // N*64
    float* x1  = h + NN * 64;                // N*64
    float* x2  = x1 + NN * 64;               // N*64
    float* x3  = x2 + NN * 64;               // N*64
    float* stats = x3 + NN * 64;             // 128
    int* cnt  = (int*)(stats + 128);         // N
    int* cur  = cnt + NN;                    // N
    int* bsum = cur + NN;                    // 64
    int* off  = bsum + 64;                   // N+1
    uintptr_t up = (uintptr_t)(off + NN + 1);
    up = (up + 7) & ~(uintptr_t)7;
    int2* edata = (int2*)up;                 // E

    const int B = 256;
    const int gElem = 2048;
    const int gRows = NN / 4;  // 25000

    // ---- CSR build + normalization ----
    hipMemsetAsync(cnt, 0, NN * sizeof(int), stream);
    count_kernel<<<gElem, B, 0, stream>>>(ei + NE, cnt);
    dis_kernel<<<512, B, 0, stream>>>(cnt, dis);
    scan_partial<<<SCAN_NBLK, B, 0, stream>>>(cnt, bsum);
    scan_bsum<<<1, 64, 0, stream>>>(bsum, off);
    scan_scatter<<<SCAN_NBLK, B, 0, stream>>>(cnt, bsum, off);
    hipMemcpyAsync(cur, off, NN * sizeof(int), hipMemcpyDeviceToDevice, stream);
    fill_kernel<<<gElem, B, 0, stream>>>(ei, dis, cur, edata);

    // ---- layer 1 ----
    gemm_k<DIN><<<gRows, B, 0, stream>>>(node_feat, W1, h);
    agg_csr<<<gRows, B, 0, stream>>>(off, edata, dis, h, x1);
    hipMemsetAsync(stats, 0, 128 * sizeof(float), stream);
    stats_kernel<<<512, B, 0, stream>>>(x1, stats);
    bn_relu_kernel<<<gElem, B, 0, stream>>>(x1, stats, g1, beta1);

    // ---- layer 2 ----
    gemm_k<HDIM><<<gRows, B, 0, stream>>>(x1, W2, h);
    agg_csr<<<gRows, B, 0, stream>>>(off, edata, dis, h, x2);
    hipMemsetAsync(stats, 0, 128 * sizeof(float), stream);
    stats_kernel<<<512, B, 0, stream>>>(x2, stats);
    bn_relu_kernel<<<gElem, B, 0, stream>>>(x2, stats, g2, beta2);

    // ---- layer 3 (b3 folded into final) ----
    gemm_k<HDIM><<<gRows, B, 0, stream>>>(x2, W3, h);
    agg_csr<<<gRows, B, 0, stream>>>(off, edata, dis, h, x3);

    // ---- JK max + final linear ----
    final_kernel<<<gRows, B, 0, stream>>>(x1, x2, x3, b3, Wf, bf, out);
}

// Round 3
// 653.291 us; speedup vs baseline: 6.6289x; 1.0616x over previous
//
#include <hip/hip_runtime.h>

#define NN 100000
#define NE 1600000
#define DIN 128
#define HDIM 64
#define DOUT 40
#define EPS 1e-5f

#define SCAN_CHUNK 2048
#define SCAN_NBLK ((NN + SCAN_CHUNK - 1) / SCAN_CHUNK)  // 49

// ---------------- CSR build ----------------
__global__ __launch_bounds__(256) void count_kernel(const int* __restrict__ dst,
                                                    int* __restrict__ cnt) {
    for (int e = blockIdx.x * blockDim.x + threadIdx.x; e < NE; e += gridDim.x * blockDim.x)
        atomicAdd(&cnt[dst[e]], 1);
}

__global__ __launch_bounds__(256) void dis_kernel(const int* __restrict__ cnt,
                                                  float* __restrict__ dis) {
    for (int i = blockIdx.x * blockDim.x + threadIdx.x; i < NN; i += gridDim.x * blockDim.x)
        dis[i] = rsqrtf((float)(cnt[i] + 1));   // +1 self loop
}

// partial sums per 2048-chunk
__global__ __launch_bounds__(256) void scan_partial(const int* __restrict__ cnt,
                                                    int* __restrict__ bsum) {
    __shared__ int ls[256];
    const int tid = threadIdx.x;
    int base = blockIdx.x * SCAN_CHUNK + tid * 8;
    int s = 0;
#pragma unroll
    for (int k = 0; k < 8; ++k) {
        int idx = base + k;
        s += (idx < NN) ? cnt[idx] : 0;
    }
    ls[tid] = s;
    __syncthreads();
    for (int off = 128; off > 0; off >>= 1) {
        if (tid < off) ls[tid] += ls[tid + off];
        __syncthreads();
    }
    if (tid == 0) bsum[blockIdx.x] = ls[0];
}

__global__ __launch_bounds__(64) void scan_bsum(int* __restrict__ bsum, int* __restrict__ off) {
    if (threadIdx.x == 0) {
        int run = 0;
        for (int i = 0; i < SCAN_NBLK; ++i) {
            int t = bsum[i];
            bsum[i] = run;
            run += t;
        }
        off[NN] = NE;
    }
}

__global__ __launch_bounds__(256) void scan_scatter(const int* __restrict__ cnt,
                                                    const int* __restrict__ bsum,
                                                    int* __restrict__ off) {
    __shared__ int part[256];
    const int tid = threadIdx.x;
    const int base = blockIdx.x * SCAN_CHUNK + tid * 8;
    int v[8];
    int s = 0;
#pragma unroll
    for (int k = 0; k < 8; ++k) {
        int idx = base + k;
        v[k] = (idx < NN) ? cnt[idx] : 0;
        s += v[k];
    }
    part[tid] = s;
    __syncthreads();
    if (tid == 0) {
        int run = 0;
        for (int i = 0; i < 256; ++i) {
            int t = part[i];
            part[i] = run;
            run += t;
        }
    }
    __syncthreads();
    int run = bsum[blockIdx.x] + part[tid];
#pragma unroll
    for (int k = 0; k < 8; ++k) {
        int idx = base + k;
        if (idx < NN) off[idx] = run;
        run += v[k];
    }
}

__global__ __launch_bounds__(256) void fill_kernel(const int* __restrict__ ei,
                                                   const float* __restrict__ dis,
                                                   int* __restrict__ cur,
                                                   int2* __restrict__ edata) {
    for (int e = blockIdx.x * blockDim.x + threadIdx.x; e < NE; e += gridDim.x * blockDim.x) {
        int s = ei[e];
        int d = ei[NE + e];
        int pos = atomicAdd(&cur[d], 1);
        edata[pos] = make_int2(s, __float_as_int(dis[s] * dis[d]));
    }
}

// ---------------- dense GEMM: h[N,64] = x[N,K] @ W[K,64] ----------------
// W column resident in VGPRs (lane = output channel); x row values are
// wave-uniform broadcast loads (readfirstlane-forced scalar base).
template <int K>
__global__ __launch_bounds__(256) void gemm_reg(const float* __restrict__ x,
                                                const float* __restrict__ W,
                                                float* __restrict__ h) {
    const int lane = threadIdx.x & 63;
    float w[K];
#pragma unroll
    for (int k = 0; k < K; ++k) w[k] = W[k * 64 + lane];
    const int wid0 = blockIdx.x * 4 + (threadIdx.x >> 6);
    const int stride = gridDim.x * 4;
    for (int row = wid0; row < NN; row += stride) {
        const float* xp = x + (long long)__builtin_amdgcn_readfirstlane(row) * K;
        float a0 = 0.f, a1 = 0.f, a2 = 0.f, a3 = 0.f;
#pragma unroll
        for (int k = 0; k < K; k += 4) {
            float4 xv = *(const float4*)(xp + k);
            a0 = fmaf(xv.x, w[k + 0], a0);
            a1 = fmaf(xv.y, w[k + 1], a1);
            a2 = fmaf(xv.z, w[k + 2], a2);
            a3 = fmaf(xv.w, w[k + 3], a3);
        }
        h[row * 64 + lane] = (a0 + a1) + (a2 + a3);
    }
}

// ---------------- CSR gather: y[n] = h[n]*dis[n]^2 + sum_in h[src]*norm ----------------
__global__ __launch_bounds__(256) void agg_csr(const int* __restrict__ off,
                                               const int2* __restrict__ edata,
                                               const float* __restrict__ dis,
                                               const float* __restrict__ h,
                                               float* __restrict__ y) {
    const int node = blockIdx.x * 4 + (threadIdx.x >> 6);  // one wave per node
    const int c = threadIdx.x & 63;
    const float s = dis[node];
    float acc = h[node * 64 + c] * s * s;
    const int jb = off[node], je = off[node + 1];
#pragma unroll 4
    for (int j = jb; j < je; ++j) {
        int2 p = edata[j];
        acc = fmaf(h[p.x * 64 + c], __int_as_float(p.y), acc);
    }
    y[node * 64 + c] = acc;
}

// ---------------- per-channel sum / sumsq ----------------
__global__ __launch_bounds__(256) void stats_kernel(const float* __restrict__ y, float* stats) {
    const int tid = threadIdx.x;
    const int c = tid & 63, rg = tid >> 6;
    float s = 0.f, s2 = 0.f;
    for (int row = blockIdx.x * 4 + rg; row < NN; row += gridDim.x * 4) {
        float v = y[row * 64 + c];
        s += v;
        s2 += v * v;
    }
    __shared__ float ls[256], ls2[256];
    ls[tid] = s; ls2[tid] = s2;
    __syncthreads();
    if (tid < 64) {
        s = ls[tid] + ls[tid + 64] + ls[tid + 128] + ls[tid + 192];
        s2 = ls2[tid] + ls2[tid + 64] + ls2[tid + 128] + ls2[tid + 192];
        atomicAdd(&stats[tid], s);
        atomicAdd(&stats[64 + tid], s2);
    }
}

// ---------------- BN (batch stats) + ReLU, in place ----------------
__global__ __launch_bounds__(256) void bn_relu_kernel(float* __restrict__ x,
                                                      const float* __restrict__ stats,
                                                      const float* __restrict__ g,
                                                      const float* __restrict__ beta) {
    const float invN = 1.0f / NN;
    for (int i = blockIdx.x * blockDim.x + threadIdx.x; i < NN * 16; i += gridDim.x * blockDim.x) {
        int q = i & 15;
        int c0 = q * 4;
        float4 v = ((const float4*)x)[i];
        float o[4] = {v.x, v.y, v.z, v.w};
#pragma unroll
        for (int j = 0; j < 4; ++j) {
            float mc = stats[c0 + j] * invN;
            float var = stats[64 + c0 + j] * invN - mc * mc;
            float sc = g[c0 + j] * rsqrtf(var + EPS);
            float sh = beta[c0 + j] - mc * sc;
            o[j] = fmaxf(fmaf(o[j], sc, sh), 0.f);
        }
        v.x = o[0]; v.y = o[1]; v.z = o[2]; v.w = o[3];
        ((float4*)x)[i] = v;
    }
}

// ---------------- JK max + final linear ----------------
__global__ __launch_bounds__(256) void final_kernel(const float* __restrict__ x1,
                                                    const float* __restrict__ x2,
                                                    const float* __restrict__ x3,
                                                    const float* __restrict__ b3,
                                                    const float* __restrict__ Wf,
                                                    const float* __restrict__ bf,
                                                    float* __restrict__ out) {
    __shared__ float m[4][64];
    const int tid = threadIdx.x;
    const int r = tid >> 6, c = tid & 63;
    const int row = blockIdx.x * 4 + r;
    int o = row * 64 + c;
    float v = fmaxf(fmaxf(x1[o], x2[o]), x3[o] + b3[c]);
    m[r][c] = v;
    __syncthreads();
    if (c < DOUT) {
        float acc = bf[c];
#pragma unroll
        for (int k = 0; k < 64; ++k) acc += m[r][k] * Wf[k * DOUT + c];
        out[row * DOUT + c] = acc;
    }
}

extern "C" void kernel_launch(void* const* d_in, const int* in_sizes, int n_in,
                              void* d_out, int out_size, void* d_ws, size_t ws_size,
                              hipStream_t stream) {
    const float* node_feat = (const float*)d_in[0];
    const int*   ei        = (const int*)d_in[1];
    const float* W1 = (const float*)d_in[2];
    const float* g1 = (const float*)d_in[4];
    const float* beta1 = (const float*)d_in[5];
    const float* W2 = (const float*)d_in[6];
    const float* g2 = (const float*)d_in[8];
    const float* beta2 = (const float*)d_in[9];
    const float* W3 = (const float*)d_in[10];
    const float* b3 = (const float*)d_in[11];
    const float* Wf = (const float*)d_in[12];
    const float* bf = (const float*)d_in[13];
    float* out = (float*)d_out;

    // workspace layout
    float* ws  = (float*)d_ws;
    float* dis = ws;                         // N
    float* h   = dis + NN;                   // N*64
    float* x1  = h + NN * 64;                // N*64
    float* x2  = x1 + NN * 64;               // N*64
    float* x3  = x2 + NN * 64;               // N*64
    float* stats = x3 + NN * 64;             // 128
    int* cnt  = (int*)(stats + 128);         // N
    int* cur  = cnt + NN;                    // N
    int* bsum = cur + NN;                    // 64
    int* off  = bsum + 64;                   // N+1
    uintptr_t up = (uintptr_t)(off + NN + 1);
    up = (up + 7) & ~(uintptr_t)7;
    int2* edata = (int2*)up;                 // E

    const int B = 256;
    const int gElem = 2048;
    const int gRows = NN / 4;   // 25000
    const int gGemm = 2048;     // 8192 waves, ~12 rows/wave

    // ---- CSR build + normalization ----
    hipMemsetAsync(cnt, 0, NN * sizeof(int), stream);
    count_kernel<<<gElem, B, 0, stream>>>(ei + NE, cnt);
    dis_kernel<<<512, B, 0, stream>>>(cnt, dis);
    scan_partial<<<SCAN_NBLK, B, 0, stream>>>(cnt, bsum);
    scan_bsum<<<1, 64, 0, stream>>>(bsum, off);
    scan_scatter<<<SCAN_NBLK, B, 0, stream>>>(cnt, bsum, off);
    hipMemcpyAsync(cur, off, NN * sizeof(int), hipMemcpyDeviceToDevice, stream);
    fill_kernel<<<gElem, B, 0, stream>>>(ei, dis, cur, edata);

    // ---- layer 1 ----
    gemm_reg<DIN><<<gGemm, B, 0, stream>>>(node_feat, W1, h);
    agg_csr<<<gRows, B, 0, stream>>>(off, edata, dis, h, x1);
    hipMemsetAsync(stats, 0, 128 * sizeof(float), stream);
    stats_kernel<<<512, B, 0, stream>>>(x1, stats);
    bn_relu_kernel<<<gElem, B, 0, stream>>>(x1, stats, g1, beta1);

    // ---- layer 2 ----
    gemm_reg<HDIM><<<gGemm, B, 0, stream>>>(x1, W2, h);
    agg_csr<<<gRows, B, 0, stream>>>(off, edata, dis, h, x2);
    hipMemsetAsync(stats, 0, 128 * sizeof(float), stream);
    stats_kernel<<<512, B, 0, stream>>>(x2, stats);
    bn_relu_kernel<<<gElem, B, 0, stream>>>(x2, stats, g2, beta2);

    // ---- layer 3 (b3 folded into final) ----
    gemm_reg<HDIM><<<gGemm, B, 0, stream>>>(x2, W3, h);
    agg_csr<<<gRows, B, 0, stream>>>(off, edata, dis, h, x3);

    // ---- JK max + final linear ----
    final_kernel<<<gRows, B, 0, stream>>>(x1, x2, x3, b3, Wf, bf, out);
}

// Round 4
// 626.797 us; speedup vs baseline: 6.9091x; 1.0423x over previous
//
#include <hip/hip_runtime.h>

#define NN 100000
#define NE 1600000
#define DIN 128
#define HDIM 64
#define DOUT 40
#define EPS 1e-5f
#define NXCD 8

#define SCAN_CHUNK 2048
#define SCAN_NBLK ((NN + SCAN_CHUNK - 1) / SCAN_CHUNK)  // 49

// ---------------- CSR build ----------------
__global__ __launch_bounds__(256) void count_kernel(const int* __restrict__ dst,
                                                    int* __restrict__ cnt) {
    for (int e = blockIdx.x * blockDim.x + threadIdx.x; e < NE; e += gridDim.x * blockDim.x)
        atomicAdd(&cnt[dst[e]], 1);
}

__global__ __launch_bounds__(256) void dis_kernel(const int* __restrict__ cnt,
                                                  float* __restrict__ dis) {
    for (int i = blockIdx.x * blockDim.x + threadIdx.x; i < NN; i += gridDim.x * blockDim.x)
        dis[i] = rsqrtf((float)(cnt[i] + 1));   // +1 self loop
}

// partial sums per 2048-chunk
__global__ __launch_bounds__(256) void scan_partial(const int* __restrict__ cnt,
                                                    int* __restrict__ bsum) {
    __shared__ int ls[256];
    const int tid = threadIdx.x;
    int base = blockIdx.x * SCAN_CHUNK + tid * 8;
    int s = 0;
#pragma unroll
    for (int k = 0; k < 8; ++k) {
        int idx = base + k;
        s += (idx < NN) ? cnt[idx] : 0;
    }
    ls[tid] = s;
    __syncthreads();
    for (int off = 128; off > 0; off >>= 1) {
        if (tid < off) ls[tid] += ls[tid + off];
        __syncthreads();
    }
    if (tid == 0) bsum[blockIdx.x] = ls[0];
}

__global__ __launch_bounds__(64) void scan_bsum(int* __restrict__ bsum, int* __restrict__ off) {
    if (threadIdx.x == 0) {
        int run = 0;
        for (int i = 0; i < SCAN_NBLK; ++i) {
            int t = bsum[i];
            bsum[i] = run;
            run += t;
        }
        off[NN] = NE;
    }
}

// scatter exclusive prefix into BOTH off and cur (cur is fill's cursor)
__global__ __launch_bounds__(256) void scan_scatter(const int* __restrict__ cnt,
                                                    const int* __restrict__ bsum,
                                                    int* __restrict__ off,
                                                    int* __restrict__ cur) {
    __shared__ int part[256];
    const int tid = threadIdx.x;
    const int base = blockIdx.x * SCAN_CHUNK + tid * 8;
    int v[8];
    int s = 0;
#pragma unroll
    for (int k = 0; k < 8; ++k) {
        int idx = base + k;
        v[k] = (idx < NN) ? cnt[idx] : 0;
        s += v[k];
    }
    part[tid] = s;
    __syncthreads();
    if (tid == 0) {
        int run = 0;
        for (int i = 0; i < 256; ++i) {
            int t = part[i];
            part[i] = run;
            run += t;
        }
    }
    __syncthreads();
    int run = bsum[blockIdx.x] + part[tid];
#pragma unroll
    for (int k = 0; k < 8; ++k) {
        int idx = base + k;
        if (idx < NN) { off[idx] = run; cur[idx] = run; }
        run += v[k];
    }
}

// XCD-sharded fill: blocks on XCD p (blockIdx%8) only file edges with dst in
// range p, so each 64B edata line is written by exactly one XCD and stays in
// that XCD's L2 until complete. Costs 8x re-read of ei (L3-resident, cheap);
// kills the 64B-per-8B write-allocate HBM traffic.
__global__ __launch_bounds__(256) void fill_kernel(const int* __restrict__ ei,
                                                   const float* __restrict__ dis,
                                                   int* __restrict__ cur,
                                                   int2* __restrict__ edata) {
    const int xcd = blockIdx.x & (NXCD - 1);
    const int lo = xcd * (NN / NXCD);
    const int hi = (xcd == NXCD - 1) ? NN : lo + (NN / NXCD);
    const int slot = blockIdx.x >> 3;
    const int nslot = gridDim.x >> 3;
    for (int e = slot * blockDim.x + threadIdx.x; e < NE; e += nslot * blockDim.x) {
        int d = ei[NE + e];
        if (d >= lo && d < hi) {
            int s = ei[e];
            int pos = atomicAdd(&cur[d], 1);
            edata[pos] = make_int2(s, __float_as_int(dis[s] * dis[d]));
        }
    }
}

// ---------------- dense GEMM: h[N,64] = x[N,K] @ W[K,64] ----------------
// W column resident in VGPRs (lane = output channel); x row values are
// wave-uniform broadcast loads.
template <int K>
__global__ __launch_bounds__(256) void gemm_reg(const float* __restrict__ x,
                                                const float* __restrict__ W,
                                                float* __restrict__ h) {
    const int lane = threadIdx.x & 63;
    float w[K];
#pragma unroll
    for (int k = 0; k < K; ++k) w[k] = W[k * 64 + lane];
    const int wid0 = blockIdx.x * 4 + (threadIdx.x >> 6);
    const int stride = gridDim.x * 4;
    for (int row = wid0; row < NN; row += stride) {
        const float* xp = x + (long long)__builtin_amdgcn_readfirstlane(row) * K;
        float a0 = 0.f, a1 = 0.f, a2 = 0.f, a3 = 0.f;
#pragma unroll
        for (int k = 0; k < K; k += 4) {
            float4 xv = *(const float4*)(xp + k);
            a0 = fmaf(xv.x, w[k + 0], a0);
            a1 = fmaf(xv.y, w[k + 1], a1);
            a2 = fmaf(xv.z, w[k + 2], a2);
            a3 = fmaf(xv.w, w[k + 3], a3);
        }
        h[row * 64 + lane] = (a0 + a1) + (a2 + a3);
    }
}

// ---------------- CSR gather: y[n] = h[n]*dis[n]^2 + sum_in h[src]*norm ----------------
__global__ __launch_bounds__(256) void agg_csr(const int* __restrict__ off,
                                               const int2* __restrict__ edata,
                                               const float* __restrict__ dis,
                                               const float* __restrict__ h,
                                               float* __restrict__ y) {
    const int node = blockIdx.x * 4 + (threadIdx.x >> 6);  // one wave per node
    const int c = threadIdx.x & 63;
    const float s = dis[node];
    float acc = h[node * 64 + c] * s * s;
    const int jb = off[node], je = off[node + 1];
#pragma unroll 8
    for (int j = jb; j < je; ++j) {
        int2 p = edata[j];
        acc = fmaf(h[p.x * 64 + c], __int_as_float(p.y), acc);
    }
    y[node * 64 + c] = acc;
}

// ---------------- per-channel sum / sumsq ----------------
__global__ __launch_bounds__(256) void stats_kernel(const float* __restrict__ y, float* stats) {
    const int tid = threadIdx.x;
    const int c = tid & 63, rg = tid >> 6;
    float s = 0.f, s2 = 0.f;
    for (int row = blockIdx.x * 4 + rg; row < NN; row += gridDim.x * 4) {
        float v = y[row * 64 + c];
        s += v;
        s2 += v * v;
    }
    __shared__ float ls[256], ls2[256];
    ls[tid] = s; ls2[tid] = s2;
    __syncthreads();
    if (tid < 64) {
        s = ls[tid] + ls[tid + 64] + ls[tid + 128] + ls[tid + 192];
        s2 = ls2[tid] + ls2[tid + 64] + ls2[tid + 128] + ls2[tid + 192];
        atomicAdd(&stats[tid], s);
        atomicAdd(&stats[64 + tid], s2);
    }
}

// ---------------- BN (batch stats) + ReLU, in place ----------------
__global__ __launch_bounds__(256) void bn_relu_kernel(float* __restrict__ x,
                                                      const float* __restrict__ stats,
                                                      const float* __restrict__ g,
                                                      const float* __restrict__ beta) {
    const float invN = 1.0f / NN;
    for (int i = blockIdx.x * blockDim.x + threadIdx.x; i < NN * 16; i += gridDim.x * blockDim.x) {
        int q = i & 15;
        int c0 = q * 4;
        float4 v = ((const float4*)x)[i];
        float o[4] = {v.x, v.y, v.z, v.w};
#pragma unroll
        for (int j = 0; j < 4; ++j) {
            float mc = stats[c0 + j] * invN;
            float var = stats[64 + c0 + j] * invN - mc * mc;
            float sc = g[c0 + j] * rsqrtf(var + EPS);
            float sh = beta[c0 + j] - mc * sc;
            o[j] = fmaxf(fmaf(o[j], sc, sh), 0.f);
        }
        v.x = o[0]; v.y = o[1]; v.z = o[2]; v.w = o[3];
        ((float4*)x)[i] = v;
    }
}

// ---------------- JK max + final linear ----------------
__global__ __launch_bounds__(256) void final_kernel(const float* __restrict__ x1,
                                                    const float* __restrict__ x2,
                                                    const float* __restrict__ x3,
                                                    const float* __restrict__ b3,
                                                    const float* __restrict__ Wf,
                                                    const float* __restrict__ bf,
                                                    float* __restrict__ out) {
    __shared__ float m[4][64];
    const int tid = threadIdx.x;
    const int r = tid >> 6, c = tid & 63;
    const int row = blockIdx.x * 4 + r;
    int o = row * 64 + c;
    float v = fmaxf(fmaxf(x1[o], x2[o]), x3[o] + b3[c]);
    m[r][c] = v;
    __syncthreads();
    if (c < DOUT) {
        float acc = bf[c];
#pragma unroll
        for (int k = 0; k < 64; ++k) acc += m[r][k] * Wf[k * DOUT + c];
        out[row * DOUT + c] = acc;
    }
}

extern "C" void kernel_launch(void* const* d_in, const int* in_sizes, int n_in,
                              void* d_out, int out_size, void* d_ws, size_t ws_size,
                              hipStream_t stream) {
    const float* node_feat = (const float*)d_in[0];
    const int*   ei        = (const int*)d_in[1];
    const float* W1 = (const float*)d_in[2];
    const float* g1 = (const float*)d_in[4];
    const float* beta1 = (const float*)d_in[5];
    const float* W2 = (const float*)d_in[6];
    const float* g2 = (const float*)d_in[8];
    const float* beta2 = (const float*)d_in[9];
    const float* W3 = (const float*)d_in[10];
    const float* b3 = (const float*)d_in[11];
    const float* Wf = (const float*)d_in[12];
    const float* bf = (const float*)d_in[13];
    float* out = (float*)d_out;

    // workspace layout
    float* ws  = (float*)d_ws;
    float* dis = ws;                         // N
    float* h   = dis + NN;                   // N*64
    float* x1  = h + NN * 64;                // N*64
    float* x2  = x1 + NN * 64;               // N*64
    float* x3  = x2 + NN * 64;               // N*64
    float* stats = x3 + NN * 64;             // 128
    int* cnt  = (int*)(stats + 128);         // N
    int* cur  = cnt + NN;                    // N
    int* bsum = cur + NN;                    // 64
    int* off  = bsum + 64;                   // N+1
    uintptr_t up = (uintptr_t)(off + NN + 1);
    up = (up + 7) & ~(uintptr_t)7;
    int2* edata = (int2*)up;                 // E

    const int B = 256;
    const int gElem = 2048;
    const int gRows = NN / 4;   // 25000
    const int gGemm = 2048;

    // ---- CSR build + normalization ----
    hipMemsetAsync(cnt, 0, NN * sizeof(int), stream);
    count_kernel<<<gElem, B, 0, stream>>>(ei + NE, cnt);
    dis_kernel<<<512, B, 0, stream>>>(cnt, dis);
    scan_partial<<<SCAN_NBLK, B, 0, stream>>>(cnt, bsum);
    scan_bsum<<<1, 64, 0, stream>>>(bsum, off);
    scan_scatter<<<SCAN_NBLK, B, 0, stream>>>(cnt, bsum, off, cur);
    fill_kernel<<<gElem, B, 0, stream>>>(ei, dis, cur, edata);

    // ---- layer 1 ----
    gemm_reg<DIN><<<gGemm, B, 0, stream>>>(node_feat, W1, h);
    agg_csr<<<gRows, B, 0, stream>>>(off, edata, dis, h, x1);
    hipMemsetAsync(stats, 0, 128 * sizeof(float), stream);
    stats_kernel<<<512, B, 0, stream>>>(x1, stats);
    bn_relu_kernel<<<gElem, B, 0, stream>>>(x1, stats, g1, beta1);

    // ---- layer 2 ----
    gemm_reg<HDIM><<<gGemm, B, 0, stream>>>(x1, W2, h);
    agg_csr<<<gRows, B, 0, stream>>>(off, edata, dis, h, x2);
    hipMemsetAsync(stats, 0, 128 * sizeof(float), stream);
    stats_kernel<<<512, B, 0, stream>>>(x2, stats);
    bn_relu_kernel<<<gElem, B, 0, stream>>>(x2, stats, g2, beta2);

    // ---- layer 3 (b3 folded into final) ----
    gemm_reg<HDIM><<<gGemm, B, 0, stream>>>(x2, W3, h);
    agg_csr<<<gRows, B, 0, stream>>>(off, edata, dis, h, x3);

    // ---- JK max + final linear ----
    final_kernel<<<gRows, B, 0, stream>>>(x1, x2, x3, b3, Wf, bf, out);
}

// Round 5
// 566.863 us; speedup vs baseline: 7.6396x; 1.1057x over previous
//
#include <hip/hip_runtime.h>

#define NN 100000
#define NE 1600000
#define DIN 128
#define HDIM 64
#define DOUT 40
#define EPS 1e-5f
#define NXCD 8

#define SCAN_CHUNK 2048
#define SCAN_NBLK ((NN + SCAN_CHUNK - 1) / SCAN_CHUNK)  // 49

__device__ __forceinline__ float bf2f(unsigned short v) {
    return __uint_as_float(((unsigned int)v) << 16);
}
__device__ __forceinline__ unsigned short f2bf(float f) {
    unsigned int u = __float_as_uint(f);
    u += 0x7FFFu + ((u >> 16) & 1u);   // round-to-nearest-even
    return (unsigned short)(u >> 16);
}

// ---------------- CSR build ----------------
__global__ __launch_bounds__(256) void count_kernel(const int* __restrict__ dst,
                                                    int* __restrict__ cnt) {
    for (int e = blockIdx.x * blockDim.x + threadIdx.x; e < NE; e += gridDim.x * blockDim.x)
        atomicAdd(&cnt[dst[e]], 1);
}

__global__ __launch_bounds__(256) void dis_kernel(const int* __restrict__ cnt,
                                                  float* __restrict__ dis) {
    for (int i = blockIdx.x * blockDim.x + threadIdx.x; i < NN; i += gridDim.x * blockDim.x)
        dis[i] = rsqrtf((float)(cnt[i] + 1));   // +1 self loop
}

__global__ __launch_bounds__(256) void scan_partial(const int* __restrict__ cnt,
                                                    int* __restrict__ bsum) {
    __shared__ int ls[256];
    const int tid = threadIdx.x;
    int base = blockIdx.x * SCAN_CHUNK + tid * 8;
    int s = 0;
#pragma unroll
    for (int k = 0; k < 8; ++k) {
        int idx = base + k;
        s += (idx < NN) ? cnt[idx] : 0;
    }
    ls[tid] = s;
    __syncthreads();
    for (int off = 128; off > 0; off >>= 1) {
        if (tid < off) ls[tid] += ls[tid + off];
        __syncthreads();
    }
    if (tid == 0) bsum[blockIdx.x] = ls[0];
}

__global__ __launch_bounds__(64) void scan_bsum(int* __restrict__ bsum, int* __restrict__ off) {
    if (threadIdx.x == 0) {
        int run = 0;
        for (int i = 0; i < SCAN_NBLK; ++i) {
            int t = bsum[i];
            bsum[i] = run;
            run += t;
        }
        off[NN] = NE;
    }
}

__global__ __launch_bounds__(256) void scan_scatter(const int* __restrict__ cnt,
                                                    const int* __restrict__ bsum,
                                                    int* __restrict__ off,
                                                    int* __restrict__ cur) {
    __shared__ int part[256];
    const int tid = threadIdx.x;
    const int base = blockIdx.x * SCAN_CHUNK + tid * 8;
    int v[8];
    int s = 0;
#pragma unroll
    for (int k = 0; k < 8; ++k) {
        int idx = base + k;
        v[k] = (idx < NN) ? cnt[idx] : 0;
        s += v[k];
    }
    part[tid] = s;
    __syncthreads();
    if (tid == 0) {
        int run = 0;
        for (int i = 0; i < 256; ++i) {
            int t = part[i];
            part[i] = run;
            run += t;
        }
    }
    __syncthreads();
    int run = bsum[blockIdx.x] + part[tid];
#pragma unroll
    for (int k = 0; k < 8; ++k) {
        int idx = base + k;
        if (idx < NN) { off[idx] = run; cur[idx] = run; }
        run += v[k];
    }
}

// XCD-sharded fill; edata is now just the src index (4B/edge).
__global__ __launch_bounds__(256) void fill_kernel(const int* __restrict__ ei,
                                                   int* __restrict__ cur,
                                                   int* __restrict__ esrc) {
    const int xcd = blockIdx.x & (NXCD - 1);
    const int lo = xcd * (NN / NXCD);
    const int hi = (xcd == NXCD - 1) ? NN : lo + (NN / NXCD);
    const int slot = blockIdx.x >> 3;
    const int nslot = gridDim.x >> 3;
    for (int e = slot * blockDim.x + threadIdx.x; e < NE; e += nslot * blockDim.x) {
        int d = ei[NE + e];
        if (d >= lo && d < hi) {
            int pos = atomicAdd(&cur[d], 1);
            esrc[pos] = ei[e];
        }
    }
}

// ---------------- dense GEMM: h2[N,64] = bf16( (x[N,K] @ W[K,64]) * dis[row] )
// x tile staged in LDS via coalesced float4 loads; W column in VGPRs.
template <int K, int TR>
__global__ __launch_bounds__(256) void gemm_lds(const float* __restrict__ x,
                                                const float* __restrict__ W,
                                                const float* __restrict__ dis,
                                                unsigned short* __restrict__ h2) {
    __shared__ float xs[TR][K];
    const int tid = threadIdx.x;
    const int lane = tid & 63;
    const int wv = tid >> 6;
    float w[K];
#pragma unroll
    for (int k = 0; k < K; ++k) w[k] = W[k * 64 + lane];

    const int row0 = blockIdx.x * TR;
    const int remRows = NN - row0;
    const int nvec = ((remRows >= TR) ? TR : remRows) * K / 4;
    const float4* srcv = (const float4*)(x + (long long)row0 * K);
    float4* dstv = (float4*)&xs[0][0];
    for (int i = tid; i < nvec; i += 256) dstv[i] = srcv[i];
    __syncthreads();

    const int rpw = TR / 4;
#pragma unroll
    for (int rr = 0; rr < rpw; ++rr) {
        const int r = wv * rpw + rr;
        const int row = row0 + r;
        if (row >= NN) break;
        float a0 = 0.f, a1 = 0.f, a2 = 0.f, a3 = 0.f;
#pragma unroll
        for (int k = 0; k < K; k += 4) {
            float4 xv = *(const float4*)&xs[r][k];
            a0 = fmaf(xv.x, w[k + 0], a0);
            a1 = fmaf(xv.y, w[k + 1], a1);
            a2 = fmaf(xv.z, w[k + 2], a2);
            a3 = fmaf(xv.w, w[k + 3], a3);
        }
        h2[row * 64 + lane] = f2bf(((a0 + a1) + (a2 + a3)) * dis[row]);
    }
}

// ---------------- CSR gather: y[n] = dis[n] * (h2[n] + sum_in h2[src]) ------
__global__ __launch_bounds__(256) void agg_csr(const int* __restrict__ off,
                                               const int* __restrict__ esrc,
                                               const float* __restrict__ dis,
                                               const unsigned short* __restrict__ h2,
                                               float* __restrict__ y) {
    const int node = blockIdx.x * 4 + (threadIdx.x >> 6);  // one wave per node
    const int c = threadIdx.x & 63;
    float acc = bf2f(h2[node * 64 + c]);
    const int jb = off[node], je = off[node + 1];
#pragma unroll 8
    for (int j = jb; j < je; ++j) {
        int s = esrc[j];
        acc += bf2f(h2[s * 64 + c]);
    }
    y[node * 64 + c] = acc * dis[node];
}

// ---------------- per-channel sum / sumsq ----------------
__global__ __launch_bounds__(256) void stats_kernel(const float* __restrict__ y, float* stats) {
    const int tid = threadIdx.x;
    const int c = tid & 63, rg = tid >> 6;
    float s = 0.f, s2 = 0.f;
    for (int row = blockIdx.x * 4 + rg; row < NN; row += gridDim.x * 4) {
        float v = y[row * 64 + c];
        s += v;
        s2 += v * v;
    }
    __shared__ float ls[256], ls2[256];
    ls[tid] = s; ls2[tid] = s2;
    __syncthreads();
    if (tid < 64) {
        s = ls[tid] + ls[tid + 64] + ls[tid + 128] + ls[tid + 192];
        s2 = ls2[tid] + ls2[tid + 64] + ls2[tid + 128] + ls2[tid + 192];
        atomicAdd(&stats[tid], s);
        atomicAdd(&stats[64 + tid], s2);
    }
}

// ---------------- BN (batch stats) + ReLU, in place ----------------
__global__ __launch_bounds__(256) void bn_relu_kernel(float* __restrict__ x,
                                                      const float* __restrict__ stats,
                                                      const float* __restrict__ g,
                                                      const float* __restrict__ beta) {
    const float invN = 1.0f / NN;
    for (int i = blockIdx.x * blockDim.x + threadIdx.x; i < NN * 16; i += gridDim.x * blockDim.x) {
        int q = i & 15;
        int c0 = q * 4;
        float4 v = ((const float4*)x)[i];
        float o[4] = {v.x, v.y, v.z, v.w};
#pragma unroll
        for (int j = 0; j < 4; ++j) {
            float mc = stats[c0 + j] * invN;
            float var = stats[64 + c0 + j] * invN - mc * mc;
            float sc = g[c0 + j] * rsqrtf(var + EPS);
            float sh = beta[c0 + j] - mc * sc;
            o[j] = fmaxf(fmaf(o[j], sc, sh), 0.f);
        }
        v.x = o[0]; v.y = o[1]; v.z = o[2]; v.w = o[3];
        ((float4*)x)[i] = v;
    }
}

// ---------------- JK max + final linear ----------------
__global__ __launch_bounds__(256) void final_kernel(const float* __restrict__ x1,
                                                    const float* __restrict__ x2,
                                                    const float* __restrict__ x3,
                                                    const float* __restrict__ b3,
                                                    const float* __restrict__ Wf,
                                                    const float* __restrict__ bf,
                                                    float* __restrict__ out) {
    __shared__ float m[4][64];
    const int tid = threadIdx.x;
    const int r = tid >> 6, c = tid & 63;
    const int row = blockIdx.x * 4 + r;
    int o = row * 64 + c;
    float v = fmaxf(fmaxf(x1[o], x2[o]), x3[o] + b3[c]);
    m[r][c] = v;
    __syncthreads();
    if (c < DOUT) {
        float acc = bf[c];
#pragma unroll
        for (int k = 0; k < 64; ++k) acc += m[r][k] * Wf[k * DOUT + c];
        out[row * DOUT + c] = acc;
    }
}

extern "C" void kernel_launch(void* const* d_in, const int* in_sizes, int n_in,
                              void* d_out, int out_size, void* d_ws, size_t ws_size,
                              hipStream_t stream) {
    const float* node_feat = (const float*)d_in[0];
    const int*   ei        = (const int*)d_in[1];
    const float* W1 = (const float*)d_in[2];
    const float* g1 = (const float*)d_in[4];
    const float* beta1 = (const float*)d_in[5];
    const float* W2 = (const float*)d_in[6];
    const float* g2 = (const float*)d_in[8];
    const float* beta2 = (const float*)d_in[9];
    const float* W3 = (const float*)d_in[10];
    const float* b3 = (const float*)d_in[11];
    const float* Wf = (const float*)d_in[12];
    const float* bf = (const float*)d_in[13];
    float* out = (float*)d_out;

    // workspace layout
    float* ws  = (float*)d_ws;
    float* dis = ws;                                       // N
    unsigned short* h2 = (unsigned short*)(dis + NN);      // N*64 bf16
    float* x1  = (float*)(h2 + NN * 64);                   // N*64 f32
    float* x2  = x1 + NN * 64;
    float* x3  = x2 + NN * 64;
    float* stats = x3 + NN * 64;                           // 128
    int* cnt  = (int*)(stats + 128);                       // N
    int* cur  = cnt + NN;                                  // N
    int* bsum = cur + NN;                                  // 64
    int* off  = bsum + 64;                                 // N+1
    int* esrc = off + NN + 1;                              // E

    const int B = 256;
    const int gElem = 2048;
    const int gRows = NN / 4;   // 25000

    // ---- CSR build + normalization ----
    hipMemsetAsync(cnt, 0, NN * sizeof(int), stream);
    count_kernel<<<gElem, B, 0, stream>>>(ei + NE, cnt);
    dis_kernel<<<512, B, 0, stream>>>(cnt, dis);
    scan_partial<<<SCAN_NBLK, B, 0, stream>>>(cnt, bsum);
    scan_bsum<<<1, 64, 0, stream>>>(bsum, off);
    scan_scatter<<<SCAN_NBLK, B, 0, stream>>>(cnt, bsum, off, cur);
    fill_kernel<<<gElem, B, 0, stream>>>(ei, cur, esrc);

    // ---- layer 1 ----
    gemm_lds<DIN, 32><<<(NN + 31) / 32, B, 0, stream>>>(node_feat, W1, dis, h2);
    agg_csr<<<gRows, B, 0, stream>>>(off, esrc, dis, h2, x1);
    hipMemsetAsync(stats, 0, 128 * sizeof(float), stream);
    stats_kernel<<<512, B, 0, stream>>>(x1, stats);
    bn_relu_kernel<<<gElem, B, 0, stream>>>(x1, stats, g1, beta1);

    // ---- layer 2 ----
    gemm_lds<HDIM, 64><<<(NN + 63) / 64, B, 0, stream>>>(x1, W2, dis, h2);
    agg_csr<<<gRows, B, 0, stream>>>(off, esrc, dis, h2, x2);
    hipMemsetAsync(stats, 0, 128 * sizeof(float), stream);
    stats_kernel<<<512, B, 0, stream>>>(x2, stats);
    bn_relu_kernel<<<gElem, B, 0, stream>>>(x2, stats, g2, beta2);

    // ---- layer 3 (b3 folded into final) ----
    gemm_lds<HDIM, 64><<<(NN + 63) / 64, B, 0, stream>>>(x2, W3, dis, h2);
    agg_csr<<<gRows, B, 0, stream>>>(off, esrc, dis, h2, x3);

    // ---- JK max + final linear ----
    final_kernel<<<gRows, B, 0, stream>>>(x1, x2, x3, b3, Wf, bf, out);
}